// Round 13
// baseline (143.832 us; speedup 1.0000x reference)
//
#include <hip/hip_runtime.h>

// ComplexResNet, round 13: R12 with waves/EU pinned to EXACTLY 3 via
// amdgpu_waves_per_eu(3,3). With max=3 the allocator has no incentive to
// clamp to 64 VGPRs for a 4th wave -> uses ~90-170 regs, eliminating the
// starvation movs that kept R11/R12 at R7's speed.

#define ALPHA 2.8853900817779268f   /* 2*log2(e) */
#define BETA (-1.4426950408889634f) /* -log2(e) */

#if __has_builtin(__builtin_amdgcn_exp2f)
#define EXP2(x) __builtin_amdgcn_exp2f(x)
#else
#define EXP2(x) exp2f(x)
#endif
#if __has_builtin(__builtin_amdgcn_rcpf)
#define RCP(x) __builtin_amdgcn_rcpf(x)
#else
#define RCP(x) (1.0f / (x))
#endif

typedef __fp16 h16;
typedef __fp16 h16x2 __attribute__((ext_vector_type(2)));
typedef __fp16 h16x8 __attribute__((ext_vector_type(8)));
typedef float  f32x4 __attribute__((ext_vector_type(4)));
typedef unsigned int u32;
typedef unsigned int ux2 __attribute__((ext_vector_type(2)));
typedef unsigned int ux4 __attribute__((ext_vector_type(4)));

__device__ __forceinline__ h16x2 pk2(float lo, float hi) {
#if __has_builtin(__builtin_amdgcn_cvt_pkrtz)
  return __builtin_amdgcn_cvt_pkrtz(lo, hi);
#else
  h16x2 r; r.x = (h16)lo; r.y = (h16)hi; return r;
#endif
}
__device__ __forceinline__ u32 pku(float lo, float hi) {
  return __builtin_bit_cast(u32, pk2(lo, hi));
}
__device__ __forceinline__ h16x2 u2h(u32 u) { return __builtin_bit_cast(h16x2, u); }
__device__ __forceinline__ h16x2 max2(h16x2 a, h16x2 b) {
  h16x2 r;
  r.x = a.x > b.x ? a.x : b.x;
  r.y = a.y > b.y ? a.y : b.y;
  return r;
}
__device__ __forceinline__ u32 umax2(u32 a, u32 b) {
  return __builtin_bit_cast(u32, max2(u2h(a), u2h(b)));
}
__device__ __forceinline__ ux4 mk4(u32 a, u32 b, u32 c, u32 d) {
  ux4 v; v.x = a; v.y = b; v.z = c; v.w = d; return v;
}
__device__ __forceinline__ f32x4 MF(ux4 a, ux4 b, f32x4 c) {
  return __builtin_amdgcn_mfma_f32_16x16x32_f16(
      __builtin_bit_cast(h16x8, a), __builtin_bit_cast(h16x8, b), c, 0, 0, 0);
}
__device__ __forceinline__ float tanh_pre(float z) {   // z pre-scaled by ALPHA
  float t = EXP2(z);
  float r = RCP(t + 1.0f);
  return fmaf(-2.0f, r, 1.0f);
}

// dword offsets in d_ws
enum {
  AF_C1 = 0,    AF_C2A = 256,  AF_C2B = 512,  AF_U1A = 768, AF_U1B = 1024,
  AF_C4A = 1280, AF_C4B = 1536, AF_S2 = 1792,
  AF_LIN = 2048,                 // 12 frags (a*4+b)*256 -> 5120
  AF_F1 = 5120, AF_F2 = 5376, AF_F3 = 5632,   // -> 5888
  AF_S1 = 5888,                  // 256 -> 6144
  BLIN = 6144,                   // 48 f32 -> 6192
  WTOT = 6192
};

__global__ void crn_prep(float* __restrict__ W,
    const float* r1c1_wr, const float* r1c1_wi, const float* r1c1_br, const float* r1c1_bi,
    const float* r1c2_wr, const float* r1c2_wi, const float* r1c2_br, const float* r1c2_bi,
    const float* r1sc_wr, const float* r1sc_wi, const float* r1sc_br, const float* r1sc_bi,
    const float* r2c1_wr, const float* r2c1_wi, const float* r2c1_br, const float* r2c1_bi,
    const float* r2c2_wr, const float* r2c2_wi, const float* r2c2_br, const float* r2c2_bi,
    const float* r2sc_wr, const float* r2sc_wi, const float* r2sc_br, const float* r2sc_bi,
    const float* la_wr, const float* la_wi, const float* la_br, const float* la_bi,
    const float* fc1_w, const float* fc1_b, const float* fc2_w, const float* fc2_b,
    const float* fc3_w, const float* fc3_b)
{
  const int t = threadIdx.x;
  u32* U = (u32*)W;
  if (t < 64) {
    const int l = t, mr = l & 15, g = l >> 4, o = mr >> 1, p = mr & 1;
    auto PK = [](float a, float b) -> u32 {
      h16x2 h; h.x = (h16)a; h.y = (h16)b; return __builtin_bit_cast(u32, h);
    };
    auto CONV = [&](int dst, const float* wr_, const float* wi_, int Cin, int ksz,
                    int tA, int tB, int O, float sc,
                    const float* br_ = nullptr, const float* bi_ = nullptr,
                    float bsc = 1.0f) {
      for (int d = 0; d < 4; ++d) {
        float vv[2];
        for (int u = 0; u < 2; ++u) {
          int tap = (d < 2) ? tA : tB;
          int ch  = (d < 2) ? (4 * g + 2 * d + u) : (4 * g + 2 * (d - 2) + u);
          int c = ch >> 1, q = ch & 1;
          float v = 0.f;
          if (tap >= 0 && o < O && c < Cin) {
            float wr = wr_[(o * Cin + c) * ksz + tap];
            float wi = wi_[(o * Cin + c) * ksz + tap];
            v = (p == 0) ? (q == 0 ? wr : -wi) : (q == 0 ? wi : wr);
            v *= sc;
          }
          if (tap < 0 && d == 2 && u == 0 && g == 0 && br_ && o < O)
            v = bsc * (p ? bi_[o] : br_[o]);
          vv[u] = v;
        }
        U[dst + l * 4 + d] = PK(vv[0], vv[1]);
      }
    };
    CONV(AF_C2A, r1c2_wr, r1c2_wi, 8, 3, 0, 1, 8, ALPHA);
    CONV(AF_C2B, r1c2_wr, r1c2_wi, 8, 3, 2, -1, 8, ALPHA, r1c2_br, r1c2_bi, ALPHA);
    CONV(AF_U1A, r2c1_wr, r2c1_wi, 8, 3, 0, 1, 4, ALPHA);
    CONV(AF_U1B, r2c1_wr, r2c1_wi, 8, 3, 2, -1, 4, ALPHA, r2c1_br, r2c1_bi, ALPHA);
    CONV(AF_C4A, r2c2_wr, r2c2_wi, 4, 3, 0, 1, 4, ALPHA);
    CONV(AF_C4B, r2c2_wr, r2c2_wi, 4, 3, 2, -1, 4, ALPHA, r2c2_br, r2c2_bi, ALPHA);
    CONV(AF_S2,  r2sc_wr, r2sc_wi, 8, 1, 0, -1, 4, 1.0f, r2sc_br, r2sc_bi, 1.0f);
    // block1 shortcut frag AS1: g==0 rows only.
    for (int d = 0; d < 4; ++d) {
      float vv[2];
      for (int u = 0; u < 2; ++u) {
        float v = 0.f;
        if (g == 0 && d == 0) {
          float wr = r1sc_wr[o], wi = r1sc_wi[o];
          v = (u == 0) ? ((p == 0) ? wr : wi) : ((p == 0) ? -wi : wr);
        } else if (g == 0 && d == 1 && u == 0) {
          v = (p ? r1sc_bi[o] : r1sc_br[o]);
        }
        vv[u] = v;
      }
      U[AF_S1 + l * 4 + d] = PK(vv[0], vv[1]);
    }
    // c1 frag: taps in dwords 0-2 (g==0 only); bias at (g==0,d==3,u==0)
    for (int d = 0; d < 4; ++d) {
      float vv[2];
      for (int u = 0; u < 2; ++u) {
        float v = 0.f;
        if (g == 0 && d < 3) {
          float wr = r1c1_wr[o * 3 + d], wi = r1c1_wi[o * 3 + d];
          v = (p == 0) ? (u == 0 ? wr : -wi) : (u == 0 ? wi : wr);
          v *= ALPHA;
        } else if (g == 0 && d == 3 && u == 0) {
          v = ALPHA * (p ? r1c1_bi[o] : r1c1_br[o]);
        }
        vv[u] = v;
      }
      U[AF_C1 + l * 4 + d] = PK(vv[0], vv[1]);
    }
    for (int a = 0; a < 3; ++a)
      for (int b = 0; b < 4; ++b) {
        int dst = AF_LIN + (a * 4 + b) * 256;
        for (int d = 0; d < 4; ++d) {
          float vv[2];
          for (int u = 0; u < 2; ++u) {
            int col = 2 * b + (d >> 1);
            int cc = 4 * g + 2 * (d & 1) + u;
            int c = cc >> 1, q = cc & 1;
            int og = 8 * a + o;
            float v = 0.f;
            if (c < 4 && og < 20) {
              int i = c * 8 + col;
              float wr = la_wr[og * 32 + i], wi = la_wi[og * 32 + i];
              v = (p == 0) ? (q == 0 ? wr : -wi) : (q == 0 ? wi : wr);
              v *= BETA;
            }
            vv[u] = v;
          }
          U[dst + l * 4 + d] = PK(vv[0], vv[1]);
        }
      }
    for (int d = 0; d < 4; ++d) {
      float vv[2];
      for (int u = 0; u < 2; ++u) {
        int idx = -1;
        if (d == 0) idx = 2 * g + u;
        else if (d == 1) idx = 8 + 2 * g + u;
        else if (d == 2 && g < 2) idx = 16 + 2 * g + u;
        float v = 0.f;
        if (idx >= 0 && idx < 20 && mr < 10) v = ALPHA * fc1_w[mr * 20 + idx];
        if (d == 3 && u == 0 && g == 0 && mr < 10) v = ALPHA * fc1_b[mr];
        vv[u] = v;
      }
      U[AF_F1 + l * 4 + d] = PK(vv[0], vv[1]);
    }
    for (int d = 0; d < 4; ++d) {
      float v2[2], v3[2];
      for (int u = 0; u < 2; ++u) {
        int ch = (d < 2) ? (4 * g + 2 * d + u) : -1;
        float a2 = 0.f, a3 = 0.f;
        if (ch >= 0 && ch < 10) {
          if (mr < 10) a2 = ALPHA * fc2_w[mr * 10 + ch];
          if (mr == 0) a3 = fc3_w[ch];
        }
        if (d == 2 && u == 0 && g == 0) {
          if (mr < 10) a2 = ALPHA * fc2_b[mr];
          if (mr == 0) a3 = fc3_b[0];
        }
        v2[u] = a2; v3[u] = a3;
      }
      U[AF_F2 + l * 4 + d] = PK(v2[0], v2[1]);
      U[AF_F3 + l * 4 + d] = PK(v3[0], v3[1]);
    }
  }
  if (t < 16) {
    int r = t, o = r >> 1, p = r & 1;
    for (int a = 0; a < 3; ++a) {
      int og = 8 * a + o;
      W[BLIN + a * 16 + r] = (og < 20) ? BETA * (p ? la_bi[og] : la_br[og]) : 0.f;
    }
  }
}

__device__ __forceinline__ float rho1(float lrp, float lip) {
  float u = 1.0f + EXP2(lrp);            // = 1 + e^{-lr_true}
  float v = 1.0f + EXP2(lip);
  float mn = fminf(u, v), mx = fmaxf(u, v);
  float t = mn * RCP(mx);
  float zz = t * t;
  float p = fmaf(zz, 0.0208351f, -0.0851330f);
  p = fmaf(zz, p, 0.1801410f);
  p = fmaf(zz, p, -0.3302995f);
  p = fmaf(zz, p, 0.9998660f);
  p = p * t;
  return (u > v) ? (1.57079632679489662f - p) : p;
}

__global__
__attribute__((amdgpu_flat_work_group_size(256, 256), amdgpu_waves_per_eu(3, 3)))
void crn_main(const float* __restrict__ x, const float* __restrict__ W,
              float* __restrict__ out, int B)
{
  const int gt = blockIdx.x * 256 + threadIdx.x;
  const int wid = gt >> 6;
  const int l = threadIdx.x & 63;
  const int g = l >> 4;
  const float* xp = x + (size_t)(wid * 16 + (l & 15)) * 66;
  const ux4* Wq = (const ux4*)W;
  const f32x4* Wf = (const f32x4*)W;
  const u32 ONE = 0x00003C00u;           // f16 1.0 in low half
  const f32x4 Z0 = {0.f, 0.f, 0.f, 0.f};

  const ux4 AC1  = Wq[(AF_C1  >> 2) + l];
  const ux4 AC2A = Wq[(AF_C2A >> 2) + l];
  const ux4 AC2B = Wq[(AF_C2B >> 2) + l];
  const ux4 AU1A = Wq[(AF_U1A >> 2) + l];
  const ux4 AU1B = Wq[(AF_U1B >> 2) + l];
  const ux4 AC4A = Wq[(AF_C4A >> 2) + l];
  const ux4 AC4B = Wq[(AF_C4B >> 2) + l];
  const ux4 AS2  = Wq[(AF_S2  >> 2) + l];
  const ux4 AS1  = Wq[(AF_S1  >> 2) + l];
  f32x4 D1 = Wf[(BLIN >> 2) + g];
  f32x4 D2 = Wf[(BLIN >> 2) + 4 + g];
  f32x4 D3 = Wf[(BLIN >> 2) + 8 + g];

  u32 xw0 = 0, xw1 = pku(xp[0], xp[33]), xw2 = pku(xp[1], xp[34]), xw3 = pku(xp[2], xp[35]);
  ux2 aP0, aP1, aP2, aP3, p10, p11, p12, uw0, uw1, uw2, Qst, Rpk, R2pk;
  aP0.x=aP0.y=aP1.x=aP1.y=aP2.x=aP2.y=aP3.x=aP3.y=0;
  p10.x=p10.y=p11.x=p11.y=p12.x=p12.y=0;
  uw0.x=uw0.y=uw1.x=uw1.y=uw2.x=uw2.y=0;
  Qst.x=Qst.y=0; Rpk.x=Rpk.y=0; R2pk.x=R2pk.y=0;

#pragma unroll
  for (int m = 0; m <= 18; ++m) {
    // ---- c1: a1 cols 2m, 2m+1 ----
    if (m <= 16) {
      aP0 = aP2; aP1 = aP3;
      {
        f32x4 d = MF(AC1, mk4(xw0, xw1, xw2, ONE), Z0);
        aP2.x = pku(tanh_pre(d.x), tanh_pre(d.y));
        aP2.y = pku(tanh_pre(d.z), tanh_pre(d.w));
      }
      if (m <= 15) {
        f32x4 d = MF(AC1, mk4(xw1, xw2, xw3, ONE), Z0);
        aP3.x = pku(tanh_pre(d.x), tanh_pre(d.y));
        aP3.y = pku(tanh_pre(d.z), tanh_pre(d.w));
      }
    }
    // ---- R(2m-1) + pool1 emit col m-1 ----
    if (m >= 1 && m <= 16) {
      f32x4 d = MF(AC2A, mk4(aP0.x, aP0.y, aP1.x, aP1.y), Z0);
      d = MF(AC2B, mk4(aP2.x, aP2.y, ONE, 0), d);
      f32x4 s = MF(AS1, mk4(xw0, ONE, 0, 0), Z0);     // sc1(x col 2m-1)
      u32 r0 = pku(tanh_pre(d.x) + s.x, tanh_pre(d.y) + s.y);
      u32 r1 = pku(tanh_pre(d.z) + s.z, tanh_pre(d.w) + s.w);
      p10 = p11; p11 = p12;
      p12.x = umax2(Rpk.x, r0); p12.y = umax2(Rpk.y, r1);
    } else if (m >= 17) {
      p10 = p11; p11 = p12; p12.x = 0; p12.y = 0;
    }
    // ---- u col m-2 ----
    if (m >= 2 && m <= 17) {
      uw0 = uw1; uw1 = uw2;
      f32x4 d = MF(AU1A, mk4(p10.x, p10.y, p11.x, p11.y), Z0);
      d = MF(AU1B, mk4(p12.x, p12.y, ONE, 0), d);
      uw2.x = pku(tanh_pre(d.x), tanh_pre(d.y));
      uw2.y = pku(tanh_pre(d.z), tanh_pre(d.w));
    } else if (m == 18) {
      uw0 = uw1; uw1 = uw2; uw2.x = 0; uw2.y = 0;
    }
    // ---- R2 col m-3 + pool2 + streamed linear ----
    if (m >= 3) {
      f32x4 d = MF(AC4A, mk4(uw0.x, uw0.y, uw1.x, uw1.y), Z0);
      d = MF(AC4B, mk4(uw2.x, uw2.y, ONE, 0), d);
      f32x4 s = MF(AS2, mk4(p10.x, p10.y, ONE, 0), Z0);   // p1 col m-3
      u32 r20 = pku(tanh_pre(d.x) + s.x, tanh_pre(d.y) + s.y);
      u32 r21 = pku(tanh_pre(d.z) + s.z, tanh_pre(d.w) + s.w);
      if (m & 1) {
        R2pk.x = r20; R2pk.y = r21;
      } else {
        ux2 Qd; Qd.x = umax2(R2pk.x, r20); Qd.y = umax2(R2pk.y, r21);
        if (m >= 6 && ((m - 6) & 3) == 0) {
          int b = (m - 6) >> 2;
          ux4 Bq = mk4(Qst.x, Qst.y, Qd.x, Qd.y);
          D1 = MF(Wq[(AF_LIN >> 2) + (0 * 4 + b) * 64 + l], Bq, D1);
          D2 = MF(Wq[(AF_LIN >> 2) + (1 * 4 + b) * 64 + l], Bq, D2);
          D3 = MF(Wq[(AF_LIN >> 2) + (2 * 4 + b) * 64 + l], Bq, D3);
        } else {
          Qst = Qd;
        }
      }
    }
    // ---- R(2m) -> Rpk (pool pending) + x slide ----
    if (m <= 15) {
      f32x4 d = MF(AC2A, mk4(aP1.x, aP1.y, aP2.x, aP2.y), Z0);
      d = MF(AC2B, mk4(aP3.x, aP3.y, ONE, 0), d);
      f32x4 s = MF(AS1, mk4(xw1, ONE, 0, 0), Z0);     // sc1(x col 2m)
      Rpk.x = pku(tanh_pre(d.x) + s.x, tanh_pre(d.y) + s.y);
      Rpk.y = pku(tanh_pre(d.z) + s.z, tanh_pre(d.w) + s.w);
      xw0 = xw2; xw1 = xw3;
      const int ca = 2 * m + 3, cb = 2 * m + 4;
      float nr0 = 0.f, ni0 = 0.f, nr1 = 0.f, ni1 = 0.f;
      if (ca <= 32) { nr0 = xp[ca]; ni0 = xp[33 + ca]; }
      if (cb <= 32) { nr1 = xp[cb]; ni1 = xp[33 + cb]; }
      xw2 = pku(nr0, ni0); xw3 = pku(nr1, ni1);
    }
  }

  // ---- head: rho -> fc1 -> fc2 -> fc3 (MFMA, biases in A via ONE rows) ----
  const ux4 AF1v = Wq[(AF_F1 >> 2) + l];
  const ux4 AF2v = Wq[(AF_F2 >> 2) + l];
  const ux4 AF3v = Wq[(AF_F3 >> 2) + l];
  u32 R1d = pku(rho1(D1.x, D1.y), rho1(D1.z, D1.w));
  u32 R2d = pku(rho1(D2.x, D2.y), rho1(D2.z, D2.w));
  u32 R3d = pku(rho1(D3.x, D3.y), rho1(D3.z, D3.w));
  f32x4 h = MF(AF1v, mk4(R1d, R2d, R3d, ONE), Z0);
  u32 H0 = pku(tanh_pre(h.x), tanh_pre(h.y));
  u32 H1 = pku(tanh_pre(h.z), tanh_pre(h.w));
  h = MF(AF2v, mk4(H0, H1, ONE, 0), Z0);
  H0 = pku(tanh_pre(h.x), tanh_pre(h.y));
  H1 = pku(tanh_pre(h.z), tanh_pre(h.w));
  h = MF(AF3v, mk4(H0, H1, ONE, 0), Z0);
  if (g == 0) out[wid * 16 + (l & 15)] = h.x;
}

extern "C" void kernel_launch(void* const* d_in, const int* in_sizes, int n_in,
                              void* d_out, int out_size, void* d_ws, size_t ws_size,
                              hipStream_t stream)
{
  const float* x = (const float*)d_in[0];
  float* W = (float*)d_ws;
  crn_prep<<<1, 256, 0, stream>>>(W,
      (const float*)d_in[1],  (const float*)d_in[2],  (const float*)d_in[3],  (const float*)d_in[4],
      (const float*)d_in[5],  (const float*)d_in[6],  (const float*)d_in[7],  (const float*)d_in[8],
      (const float*)d_in[9],  (const float*)d_in[10], (const float*)d_in[11], (const float*)d_in[12],
      (const float*)d_in[13], (const float*)d_in[14], (const float*)d_in[15], (const float*)d_in[16],
      (const float*)d_in[17], (const float*)d_in[18], (const float*)d_in[19], (const float*)d_in[20],
      (const float*)d_in[21], (const float*)d_in[22], (const float*)d_in[23], (const float*)d_in[24],
      (const float*)d_in[25], (const float*)d_in[26], (const float*)d_in[27], (const float*)d_in[28],
      (const float*)d_in[29], (const float*)d_in[30], (const float*)d_in[31], (const float*)d_in[32],
      (const float*)d_in[33], (const float*)d_in[34]);
  const int B = in_sizes[0] / 66;
  const int nblk = B / 64;          // 64 samples per 256-thread block (16/wave)
  crn_main<<<nblk, 256, 0, stream>>>(x, W, (float*)d_out, B);
}

// Round 14
// 138.973 us; speedup vs baseline: 1.0350x; 1.0350x over previous
//
#include <hip/hip_runtime.h>

// ComplexResNet, round 14: restore round-7 kernel verbatim (empirical best,
// 139.2us). R8-R13 explored 4-wave/register-diet/pin variants; all landed
// 142-165us. R7 config: unrolled MFMA cascade, launch_bounds(256,3),
// VALU sc1 via fdot2, biases in C-init.

#define ALPHA 2.8853900817779268f   /* 2*log2(e) */
#define BETA (-1.4426950408889634f) /* -log2(e) */

#if __has_builtin(__builtin_amdgcn_exp2f)
#define EXP2(x) __builtin_amdgcn_exp2f(x)
#else
#define EXP2(x) exp2f(x)
#endif
#if __has_builtin(__builtin_amdgcn_rcpf)
#define RCP(x) __builtin_amdgcn_rcpf(x)
#else
#define RCP(x) (1.0f / (x))
#endif

typedef __fp16 h16;
typedef __fp16 h16x2 __attribute__((ext_vector_type(2)));
typedef __fp16 h16x8 __attribute__((ext_vector_type(8)));
typedef float  f32x4 __attribute__((ext_vector_type(4)));
typedef unsigned int u32;
typedef unsigned int ux2 __attribute__((ext_vector_type(2)));
typedef unsigned int ux4 __attribute__((ext_vector_type(4)));

__device__ __forceinline__ h16x2 pk2(float lo, float hi) {
#if __has_builtin(__builtin_amdgcn_cvt_pkrtz)
  return __builtin_amdgcn_cvt_pkrtz(lo, hi);
#else
  h16x2 r; r.x = (h16)lo; r.y = (h16)hi; return r;
#endif
}
__device__ __forceinline__ u32 pku(float lo, float hi) {
  return __builtin_bit_cast(u32, pk2(lo, hi));
}
__device__ __forceinline__ h16x2 u2h(u32 u) { return __builtin_bit_cast(h16x2, u); }
__device__ __forceinline__ float cdot(h16x2 a, h16x2 b, float c) {
#if __has_builtin(__builtin_amdgcn_fdot2)
  return __builtin_amdgcn_fdot2(a, b, c, false);
#else
  return fmaf((float)a.x, (float)b.x, fmaf((float)a.y, (float)b.y, c));
#endif
}
__device__ __forceinline__ ux4 mk4(u32 a, u32 b, u32 c, u32 d) {
  ux4 v; v.x = a; v.y = b; v.z = c; v.w = d; return v;
}
__device__ __forceinline__ f32x4 MF(ux4 a, ux4 b, f32x4 c) {
  return __builtin_amdgcn_mfma_f32_16x16x32_f16(
      __builtin_bit_cast(h16x8, a), __builtin_bit_cast(h16x8, b), c, 0, 0, 0);
}
__device__ __forceinline__ float tanh_pre(float z) {   // z pre-scaled by ALPHA
  float t = EXP2(z);
  float r = RCP(t + 1.0f);
  return fmaf(-2.0f, r, 1.0f);
}

// dword offsets in d_ws
enum {
  AF_C1 = 0,    AF_C2A = 256,  AF_C2B = 512,  AF_U1A = 768, AF_U1B = 1024,
  AF_C4A = 1280, AF_C4B = 1536, AF_S2 = 1792,
  AF_LIN = 2048,                 // 12 frags (a*4+b)*256, ends 5120
  AF_F1 = 5120, AF_F2 = 5376, AF_F3 = 5632,
  BC1 = 5888, BC2 = 5904, BU1 = 5920, BC4 = 5936, BS2 = 5952, BSC1 = 5968,
  BLIN = 5984, BF1 = 6032, BF2 = 6048, BF3 = 6064, SC1C = 6080, WTOT = 6096
};

__global__ void crn_prep(float* __restrict__ W,
    const float* r1c1_wr, const float* r1c1_wi, const float* r1c1_br, const float* r1c1_bi,
    const float* r1c2_wr, const float* r1c2_wi, const float* r1c2_br, const float* r1c2_bi,
    const float* r1sc_wr, const float* r1sc_wi, const float* r1sc_br, const float* r1sc_bi,
    const float* r2c1_wr, const float* r2c1_wi, const float* r2c1_br, const float* r2c1_bi,
    const float* r2c2_wr, const float* r2c2_wi, const float* r2c2_br, const float* r2c2_bi,
    const float* r2sc_wr, const float* r2sc_wi, const float* r2sc_br, const float* r2sc_bi,
    const float* la_wr, const float* la_wi, const float* la_br, const float* la_bi,
    const float* fc1_w, const float* fc1_b, const float* fc2_w, const float* fc2_b,
    const float* fc3_w, const float* fc3_b)
{
  const int t = threadIdx.x;
  u32* U = (u32*)W;
  if (t < 64) {
    const int l = t, mr = l & 15, g = l >> 4, o = mr >> 1, p = mr & 1;
    auto PK = [](float a, float b) -> u32 {
      h16x2 h; h.x = (h16)a; h.y = (h16)b; return __builtin_bit_cast(u32, h);
    };
    auto CONV = [&](int dst, const float* wr_, const float* wi_, int Cin, int ksz,
                    int tA, int tB, int O, float sc) {
      for (int d = 0; d < 4; ++d) {
        float vv[2];
        for (int u = 0; u < 2; ++u) {
          int tap = (d < 2) ? tA : tB;
          int ch  = (d < 2) ? (4 * g + 2 * d + u) : (4 * g + 2 * (d - 2) + u);
          int c = ch >> 1, q = ch & 1;
          float v = 0.f;
          if (tap >= 0 && o < O && c < Cin) {
            float wr = wr_[(o * Cin + c) * ksz + tap];
            float wi = wi_[(o * Cin + c) * ksz + tap];
            v = (p == 0) ? (q == 0 ? wr : -wi) : (q == 0 ? wi : wr);
            v *= sc;
          }
          vv[u] = v;
        }
        U[dst + l * 4 + d] = PK(vv[0], vv[1]);
      }
    };
    CONV(AF_C2A, r1c2_wr, r1c2_wi, 8, 3, 0, 1, 8, ALPHA);
    CONV(AF_C2B, r1c2_wr, r1c2_wi, 8, 3, 2, -1, 8, ALPHA);
    CONV(AF_U1A, r2c1_wr, r2c1_wi, 8, 3, 0, 1, 4, ALPHA);
    CONV(AF_U1B, r2c1_wr, r2c1_wi, 8, 3, 2, -1, 4, ALPHA);
    CONV(AF_C4A, r2c2_wr, r2c2_wi, 4, 3, 0, 1, 4, ALPHA);
    CONV(AF_C4B, r2c2_wr, r2c2_wi, 4, 3, 2, -1, 4, ALPHA);
    CONV(AF_S2,  r2sc_wr, r2sc_wi, 8, 1, 0, -1, 4, 1.0f);
    for (int d = 0; d < 4; ++d) {
      float vv[2];
      for (int u = 0; u < 2; ++u) {
        float v = 0.f;
        if (g == 0 && d < 3) {
          float wr = r1c1_wr[o * 3 + d], wi = r1c1_wi[o * 3 + d];
          v = (p == 0) ? (u == 0 ? wr : -wi) : (u == 0 ? wi : wr);
          v *= ALPHA;
        }
        vv[u] = v;
      }
      U[AF_C1 + l * 4 + d] = PK(vv[0], vv[1]);
    }
    for (int a = 0; a < 3; ++a)
      for (int b = 0; b < 4; ++b) {
        int dst = AF_LIN + (a * 4 + b) * 256;
        for (int d = 0; d < 4; ++d) {
          float vv[2];
          for (int u = 0; u < 2; ++u) {
            int col = 2 * b + (d >> 1);
            int cc = 4 * g + 2 * (d & 1) + u;
            int c = cc >> 1, q = cc & 1;
            int og = 8 * a + o;
            float v = 0.f;
            if (c < 4 && og < 20) {
              int i = c * 8 + col;
              float wr = la_wr[og * 32 + i], wi = la_wi[og * 32 + i];
              v = (p == 0) ? (q == 0 ? wr : -wi) : (q == 0 ? wi : wr);
              v *= BETA;
            }
            vv[u] = v;
          }
          U[dst + l * 4 + d] = PK(vv[0], vv[1]);
        }
      }
    for (int d = 0; d < 4; ++d) {
      float vv[2];
      for (int u = 0; u < 2; ++u) {
        int idx = -1;
        if (d == 0) idx = 2 * g + u;
        else if (d == 1) idx = 8 + 2 * g + u;
        else if (d == 2 && g < 2) idx = 16 + 2 * g + u;
        float v = 0.f;
        if (idx >= 0 && idx < 20 && mr < 10) v = ALPHA * fc1_w[mr * 20 + idx];
        vv[u] = v;
      }
      U[AF_F1 + l * 4 + d] = PK(vv[0], vv[1]);
    }
    for (int d = 0; d < 4; ++d) {
      float v2[2], v3[2];
      for (int u = 0; u < 2; ++u) {
        int ch = (d < 2) ? (4 * g + 2 * d + u) : -1;
        float a2 = 0.f, a3 = 0.f;
        if (ch >= 0 && ch < 10) {
          if (mr < 10) a2 = ALPHA * fc2_w[mr * 10 + ch];
          if (mr == 0) a3 = fc3_w[ch];
        }
        v2[u] = a2; v3[u] = a3;
      }
      U[AF_F2 + l * 4 + d] = PK(v2[0], v2[1]);
      U[AF_F3 + l * 4 + d] = PK(v3[0], v3[1]);
    }
  }
  if (t < 16) {
    int r = t, o = r >> 1, p = r & 1;
    W[BC1 + r]  = ALPHA * (p ? r1c1_bi[o] : r1c1_br[o]);
    W[BC2 + r]  = ALPHA * (p ? r1c2_bi[o] : r1c2_br[o]);
    W[BU1 + r]  = (o < 4) ? ALPHA * (p ? r2c1_bi[o] : r2c1_br[o]) : 0.f;
    W[BC4 + r]  = (o < 4) ? ALPHA * (p ? r2c2_bi[o] : r2c2_br[o]) : 0.f;
    W[BS2 + r]  = (o < 4) ? (p ? r2sc_bi[o] : r2sc_br[o]) : 0.f;
    W[BSC1 + r] = (p ? r1sc_bi[o] : r1sc_br[o]);
    for (int a = 0; a < 3; ++a) {
      int og = 8 * a + o;
      W[BLIN + a * 16 + r] = (og < 20) ? BETA * (p ? la_bi[og] : la_br[og]) : 0.f;
    }
    W[BF1 + r] = (r < 10) ? ALPHA * fc1_b[r] : 0.f;
    W[BF2 + r] = (r < 10) ? ALPHA * fc2_b[r] : 0.f;
    W[BF3 + r] = (r == 0) ? fc3_b[0] : 0.f;
    {
      float wr = r1sc_wr[o], wi = r1sc_wi[o];
      float c1c = (p == 0) ? wr : wi;
      float c2c = (p == 0) ? -wi : wr;
      h16x2 h; h.x = (h16)c1c; h.y = (h16)c2c;
      ((u32*)W)[SC1C + r] = __builtin_bit_cast(u32, h);
    }
  }
}

__device__ __forceinline__ float rho1(float lrp, float lip) {
  float u = 1.0f + EXP2(lrp);            // = 1 + e^{-lr_true}
  float v = 1.0f + EXP2(lip);
  float mn = fminf(u, v), mx = fmaxf(u, v);
  float t = mn * RCP(mx);
  float zz = t * t;
  float p = fmaf(zz, 0.0208351f, -0.0851330f);
  p = fmaf(zz, p, 0.1801410f);
  p = fmaf(zz, p, -0.3302995f);
  p = fmaf(zz, p, 0.9998660f);
  p = p * t;
  return (u > v) ? (1.57079632679489662f - p) : p;
}

__global__ __launch_bounds__(256, 3)
void crn_main(const float* __restrict__ x, const float* __restrict__ W,
              float* __restrict__ out, int B)
{
  const int gt = blockIdx.x * 256 + threadIdx.x;
  const int wid = gt >> 6;
  const int l = threadIdx.x & 63;
  const int g = l >> 4;
  const float* xp = x + (size_t)(wid * 16 + (l & 15)) * 66;
  const ux4* Wq = (const ux4*)W;
  const f32x4* Wf = (const f32x4*)W;

  const ux4 AC1  = Wq[(AF_C1  >> 2) + l];
  const ux4 AC2A = Wq[(AF_C2A >> 2) + l];
  const ux4 AC2B = Wq[(AF_C2B >> 2) + l];
  const ux4 AU1A = Wq[(AF_U1A >> 2) + l];
  const ux4 AU1B = Wq[(AF_U1B >> 2) + l];
  const ux4 AC4A = Wq[(AF_C4A >> 2) + l];
  const ux4 AC4B = Wq[(AF_C4B >> 2) + l];
  const ux4 AS2  = Wq[(AF_S2  >> 2) + l];
  const f32x4 bC1 = Wf[(BC1 >> 2) + g];
  const f32x4 bC2 = Wf[(BC2 >> 2) + g];
  const f32x4 bU1 = Wf[(BU1 >> 2) + g];
  const f32x4 bC4 = Wf[(BC4 >> 2) + g];
  const f32x4 bS2 = Wf[(BS2 >> 2) + g];
  const f32x4 bSC = Wf[(BSC1 >> 2) + g];
  const ux4 SCC = Wq[(SC1C >> 2) + g];
  f32x4 D1 = Wf[(BLIN >> 2) + g];
  f32x4 D2 = Wf[(BLIN >> 2) + 4 + g];
  f32x4 D3 = Wf[(BLIN >> 2) + 8 + g];

  u32 xw0 = 0, xw1 = pku(xp[0], xp[33]), xw2 = pku(xp[1], xp[34]), xw3 = pku(xp[2], xp[35]);
  ux2 aP0, aP1, aP2, aP3, p10, p11, p12, uw0, uw1, uw2, Qst;
  aP0.x=aP0.y=aP1.x=aP1.y=aP2.x=aP2.y=aP3.x=aP3.y=0;
  p10.x=p10.y=p11.x=p11.y=p12.x=p12.y=0;
  uw0.x=uw0.y=uw1.x=uw1.y=uw2.x=uw2.y=0;
  Qst.x=Qst.y=0;
  f32x4 Rst, R2st;
  Rst.x=Rst.y=Rst.z=Rst.w=0.f; R2st = Rst;

#pragma unroll
  for (int m = 0; m <= 18; ++m) {
    // ---- c1: a1 cols 2m, 2m+1 ----
    if (m <= 16) {
      aP0 = aP2; aP1 = aP3;
      {
        f32x4 d = MF(AC1, mk4(xw0, xw1, xw2, 0), bC1);
        aP2.x = pku(tanh_pre(d.x), tanh_pre(d.y));
        aP2.y = pku(tanh_pre(d.z), tanh_pre(d.w));
      }
      if (m <= 15) {
        f32x4 d = MF(AC1, mk4(xw1, xw2, xw3, 0), bC1);
        aP3.x = pku(tanh_pre(d.x), tanh_pre(d.y));
        aP3.y = pku(tanh_pre(d.z), tanh_pre(d.w));
      }
    }
    // ---- R(2m-1) + pool1 emit col m-1 ----
    if (m >= 1 && m <= 16) {
      f32x4 d = MF(AC2A, mk4(aP0.x, aP0.y, aP1.x, aP1.y), bC2);
      d = MF(AC2B, mk4(aP2.x, aP2.y, 0, 0), d);
      h16x2 xh = u2h(xw0);
      f32x4 r;
      r.x = tanh_pre(d.x) + cdot(xh, u2h(SCC.x), bSC.x);
      r.y = tanh_pre(d.y) + cdot(xh, u2h(SCC.y), bSC.y);
      r.z = tanh_pre(d.z) + cdot(xh, u2h(SCC.z), bSC.z);
      r.w = tanh_pre(d.w) + cdot(xh, u2h(SCC.w), bSC.w);
      p10 = p11; p11 = p12;
      float m0 = fmaxf(Rst.x, r.x), m1 = fmaxf(Rst.y, r.y);
      float m2 = fmaxf(Rst.z, r.z), m3 = fmaxf(Rst.w, r.w);
      p12.x = pku(m0, m1); p12.y = pku(m2, m3);
    } else if (m >= 17) {
      p10 = p11; p11 = p12; p12.x = 0; p12.y = 0;
    }
    // ---- u col m-2 ----
    if (m >= 2 && m <= 17) {
      uw0 = uw1; uw1 = uw2;
      f32x4 d = MF(AU1A, mk4(p10.x, p10.y, p11.x, p11.y), bU1);
      d = MF(AU1B, mk4(p12.x, p12.y, 0, 0), d);
      uw2.x = pku(tanh_pre(d.x), tanh_pre(d.y));
      uw2.y = pku(tanh_pre(d.z), tanh_pre(d.w));
    } else if (m == 18) {
      uw0 = uw1; uw1 = uw2; uw2.x = 0; uw2.y = 0;
    }
    // ---- R2 col m-3 + pool2 + streamed linear ----
    if (m >= 3) {
      f32x4 d = MF(AC4A, mk4(uw0.x, uw0.y, uw1.x, uw1.y), bC4);
      d = MF(AC4B, mk4(uw2.x, uw2.y, 0, 0), d);
      f32x4 s = MF(AS2, mk4(p10.x, p10.y, 0, 0), bS2);   // p1 col m-3
      f32x4 r2;
      r2.x = tanh_pre(d.x) + s.x;
      r2.y = tanh_pre(d.y) + s.y;
      r2.z = tanh_pre(d.z) + s.z;
      r2.w = tanh_pre(d.w) + s.w;
      if (m & 1) {
        R2st = r2;
      } else {
        float m0 = fmaxf(R2st.x, r2.x), m1 = fmaxf(R2st.y, r2.y);
        float m2 = fmaxf(R2st.z, r2.z), m3 = fmaxf(R2st.w, r2.w);
        ux2 Qd; Qd.x = pku(m0, m1); Qd.y = pku(m2, m3);
        if (m >= 6 && ((m - 6) & 3) == 0) {
          int b = (m - 6) >> 2;
          ux4 Bq = mk4(Qst.x, Qst.y, Qd.x, Qd.y);
          D1 = MF(Wq[(AF_LIN >> 2) + (0 * 4 + b) * 64 + l], Bq, D1);
          D2 = MF(Wq[(AF_LIN >> 2) + (1 * 4 + b) * 64 + l], Bq, D2);
          D3 = MF(Wq[(AF_LIN >> 2) + (2 * 4 + b) * 64 + l], Bq, D3);
        } else {
          Qst = Qd;
        }
      }
    }
    // ---- R(2m) -> Rst (pool pending) + x slide ----
    if (m <= 15) {
      f32x4 d = MF(AC2A, mk4(aP1.x, aP1.y, aP2.x, aP2.y), bC2);
      d = MF(AC2B, mk4(aP3.x, aP3.y, 0, 0), d);
      h16x2 xh = u2h(xw1);
      Rst.x = tanh_pre(d.x) + cdot(xh, u2h(SCC.x), bSC.x);
      Rst.y = tanh_pre(d.y) + cdot(xh, u2h(SCC.y), bSC.y);
      Rst.z = tanh_pre(d.z) + cdot(xh, u2h(SCC.z), bSC.z);
      Rst.w = tanh_pre(d.w) + cdot(xh, u2h(SCC.w), bSC.w);
      xw0 = xw2; xw1 = xw3;
      const int ca = 2 * m + 3, cb = 2 * m + 4;
      float nr0 = 0.f, ni0 = 0.f, nr1 = 0.f, ni1 = 0.f;
      if (ca <= 32) { nr0 = xp[ca]; ni0 = xp[33 + ca]; }
      if (cb <= 32) { nr1 = xp[cb]; ni1 = xp[33 + cb]; }
      xw2 = pku(nr0, ni0); xw3 = pku(nr1, ni1);
    }
  }

  // ---- head: rho -> fc1 -> fc2 -> fc3 (MFMA) ----
  const ux4 AF1v = Wq[(AF_F1 >> 2) + l];
  const ux4 AF2v = Wq[(AF_F2 >> 2) + l];
  const ux4 AF3v = Wq[(AF_F3 >> 2) + l];
  const f32x4 bF1 = Wf[(BF1 >> 2) + g];
  const f32x4 bF2 = Wf[(BF2 >> 2) + g];
  const f32x4 bF3 = Wf[(BF3 >> 2) + g];
  u32 R1d = pku(rho1(D1.x, D1.y), rho1(D1.z, D1.w));
  u32 R2d = pku(rho1(D2.x, D2.y), rho1(D2.z, D2.w));
  u32 R3d = pku(rho1(D3.x, D3.y), rho1(D3.z, D3.w));
  f32x4 h = MF(AF1v, mk4(R1d, R2d, R3d, 0), bF1);
  u32 H0 = pku(tanh_pre(h.x), tanh_pre(h.y));
  u32 H1 = pku(tanh_pre(h.z), tanh_pre(h.w));
  h = MF(AF2v, mk4(H0, H1, 0, 0), bF2);
  H0 = pku(tanh_pre(h.x), tanh_pre(h.y));
  H1 = pku(tanh_pre(h.z), tanh_pre(h.w));
  h = MF(AF3v, mk4(H0, H1, 0, 0), bF3);
  if (g == 0) out[wid * 16 + (l & 15)] = h.x;
}

extern "C" void kernel_launch(void* const* d_in, const int* in_sizes, int n_in,
                              void* d_out, int out_size, void* d_ws, size_t ws_size,
                              hipStream_t stream)
{
  const float* x = (const float*)d_in[0];
  float* W = (float*)d_ws;
  crn_prep<<<1, 256, 0, stream>>>(W,
      (const float*)d_in[1],  (const float*)d_in[2],  (const float*)d_in[3],  (const float*)d_in[4],
      (const float*)d_in[5],  (const float*)d_in[6],  (const float*)d_in[7],  (const float*)d_in[8],
      (const float*)d_in[9],  (const float*)d_in[10], (const float*)d_in[11], (const float*)d_in[12],
      (const float*)d_in[13], (const float*)d_in[14], (const float*)d_in[15], (const float*)d_in[16],
      (const float*)d_in[17], (const float*)d_in[18], (const float*)d_in[19], (const float*)d_in[20],
      (const float*)d_in[21], (const float*)d_in[22], (const float*)d_in[23], (const float*)d_in[24],
      (const float*)d_in[25], (const float*)d_in[26], (const float*)d_in[27], (const float*)d_in[28],
      (const float*)d_in[29], (const float*)d_in[30], (const float*)d_in[31], (const float*)d_in[32],
      (const float*)d_in[33], (const float*)d_in[34]);
  const int B = in_sizes[0] / 66;
  const int nblk = B / 64;          // 64 samples per 256-thread block (16/wave)
  crn_main<<<nblk, 256, 0, stream>>>(x, W, (float*)d_out, B);
}